// Round 4
// baseline (255.907 us; speedup 1.0000x reference)
//
#include <hip/hip_runtime.h>
#include <cmath>

// Problem constants (B=4096, D=256, P=100, K=10, n=2B=8192, T=0.2)
#define BB   4096
#define DD   256
#define NN   8192
#define PP   100
#define KK   10

typedef _Float16 f16x8  __attribute__((ext_vector_type(8)));
typedef float    f32x16 __attribute__((ext_vector_type(16)));

// ---------------- workspace layout (bytes) ----------------
constexpr size_t OFF_DPART = 0;        // 64 double
constexpr size_t OFF_PPART = 512;      // 64 double
constexpr size_t OFF_CNT   = 1024;     // 100 int
constexpr size_t OFF_MU    = 1536;     // 100 f32
constexpr size_t OFF_SD    = 2048;     // 100 f32
constexpr size_t OFF_RWN   = 2560;     // 10000 f32 -> 42560
constexpr size_t OFF_R     = 42560;    // 10000 f32 -> 82560
constexpr size_t OFF_PI    = 82560;    // 8192 int  (sorted pos -> orig)
constexpr size_t OFF_INVP  = 115328;   // 8192 int  (orig -> sorted pos)
constexpr size_t OFF_HQP   = 148096;   // 8192 int  (class at sorted pos)
constexpr size_t OFF_CTAB  = 180864;   // 8192*100 f32 -> 3457664
constexpr size_t OFF_G     = 3457664;  // 8192*256 f16 fragment-packed (16B aligned)

// Fragment-packed G layout for mfma_f32_32x32x16_f16:
// element (row p, k) at ((p>>5)*16 + (k>>4))*512 + ((k>>3)&1)*256 + (p&31)*8 + (k&7)
__device__ __forceinline__ int packed_addr(int p, int k) {
    return (((p >> 5) * 16 + (k >> 4)) << 9) + (((k >> 3) & 1) << 8) + ((p & 31) << 3) + (k & 7);
}

// ---------------- sort prep: zeros + histogram + scan + counting-sort scatter ----
__global__ void sortprep_kernel(const int* __restrict__ hq, int* __restrict__ cnt,
                                int* __restrict__ pi, int* __restrict__ invp,
                                int* __restrict__ hqp,
                                double* __restrict__ dpart, double* __restrict__ ppart) {
    __shared__ int sc[PP], so[PP];
    const int t = threadIdx.x;  // 256
    if (t < PP) sc[t] = 0;
    if (t < 64) { dpart[t] = 0.0; ppart[t] = 0.0; }
    __syncthreads();
    for (int i = t; i < NN; i += 256) atomicAdd(&sc[hq[i]], 1);
    __syncthreads();
    if (t < PP) cnt[t] = sc[t];
    if (t == 0) {
        int run = 0;
        for (int c = 0; c < PP; ++c) { so[c] = run; run += sc[c]; }
    }
    __syncthreads();
    for (int i = t; i < NN; i += 256) {
        int c = hq[i];
        int d = atomicAdd(&so[c], 1);
        pi[d] = i;
        invp[i] = d;
        hqp[d] = c;
    }
}

// ---------------- normalize x / x_aug rows -> packed f16 Gp, pos dot ----------
__global__ void normalize_kernel(const float* __restrict__ x, const float* __restrict__ xa,
                                 const int* __restrict__ invp,
                                 _Float16* __restrict__ Gp, double* __restrict__ ppart) {
    const int i = blockIdx.x;       // 0..4095 (source row)
    const int t = threadIdx.x;      // 0..255 == D
    float v1 = x[(size_t)i * DD + t];
    float v2 = xa[(size_t)i * DD + t];
    float a = v1 * v1, b = v2 * v2, c = v1 * v2;
#pragma unroll
    for (int off = 32; off > 0; off >>= 1) {
        a += __shfl_down(a, off);
        b += __shfl_down(b, off);
        c += __shfl_down(c, off);
    }
    __shared__ float sa[4], sb[4], sc[4];
    const int lane = t & 63, wv = t >> 6;
    if (lane == 0) { sa[wv] = a; sb[wv] = b; sc[wv] = c; }
    __syncthreads();
    float ta = sa[0] + sa[1] + sa[2] + sa[3];
    float tb = sb[0] + sb[1] + sb[2] + sb[3];
    float tc = sc[0] + sc[1] + sc[2] + sc[3];
    float d1 = fmaxf(sqrtf(ta), 1e-12f);
    float d2 = fmaxf(sqrtf(tb), 1e-12f);
    const int p1 = invp[i];
    const int p2 = invp[i + BB];
    Gp[packed_addr(p1, t)] = (_Float16)(v1 / d1);
    Gp[packed_addr(p2, t)] = (_Float16)(v2 / d2);
    if (t == 0) atomicAdd(&ppart[i & 63], (double)(tc / (d1 * d2)));
}

// ---------------- fused proto-norm + pd row + per-class stats ----------------
// Block a: normalize pw row a, dot vs all (re-normalized) rows b -> pdrow,
// then stats over row a's multiset { pd[a][b] x (cnt[b]-(b==a)) } U {0}.
__global__ void pdstats_kernel(const float* __restrict__ pw, const int* __restrict__ cnt,
                               float* __restrict__ rwn, float* __restrict__ mu,
                               float* __restrict__ sd) {
    const int a = blockIdx.x;   // 0..99
    const int t = threadIdx.x;  // 0..127
    __shared__ float wa[DD];
    __shared__ float pdrow[PP];
    __shared__ float r4[4];
    float a0 = pw[(size_t)a * DD + t], a1 = pw[(size_t)a * DD + t + 128];
    float ss = a0 * a0 + a1 * a1;
#pragma unroll
    for (int off = 32; off > 0; off >>= 1) ss += __shfl_down(ss, off);
    if ((t & 63) == 0) r4[t >> 6] = ss;
    __syncthreads();
    float na = fmaxf(sqrtf(r4[0] + r4[1]), 1e-12f);
    wa[t] = a0 / na;
    wa[t + 128] = a1 / na;
    __syncthreads();
    for (int b = 0; b < PP; ++b) {
        float p0 = pw[(size_t)b * DD + t], p1 = pw[(size_t)b * DD + t + 128];
        float sbb = p0 * p0 + p1 * p1;
        float sab = wa[t] * p0 + wa[t + 128] * p1;
#pragma unroll
        for (int off = 32; off > 0; off >>= 1) {
            sbb += __shfl_down(sbb, off);
            sab += __shfl_down(sab, off);
        }
        if ((t & 63) == 0) { r4[t >> 6] = sbb; r4[2 + (t >> 6)] = sab; }
        __syncthreads();
        if (t == 0) {
            float nb = fmaxf(sqrtf(r4[0] + r4[1]), 1e-12f);
            pdrow[b] = 1.0f - (r4[2] + r4[3]) / nb;
        }
        __syncthreads();
    }
    if (t < 64) {
        const int lane = t;
        float vmin = 0.f, vmax = 0.f;  // eye-zero always in multiset
        for (int b = lane; b < PP; b += 64) {
            int cc = cnt[b] - (b == a ? 1 : 0);
            if (cc > 0) {
                float v = pdrow[b];
                vmin = fminf(vmin, v);
                vmax = fmaxf(vmax, v);
            }
        }
#pragma unroll
        for (int off = 32; off > 0; off >>= 1) {
            vmin = fminf(vmin, __shfl_xor(vmin, off));
            vmax = fmaxf(vmax, __shfl_xor(vmax, off));
        }
        const float den = vmax - vmin;
        const float inv = (den > 0.f) ? 1.f / den : 0.f;
        double s1 = 0.0, s2 = 0.0;
        for (int b = lane; b < PP; b += 64) {
            float v = (pdrow[b] - vmin) * inv;
            rwn[a * PP + b] = v;
            int cc = cnt[b] - (b == a ? 1 : 0);
            if (cc > 0) { double dv = v; s1 += cc * dv; s2 += cc * dv * dv; }
        }
        if (lane == 0) { double v0 = (0.0 - (double)vmin) * inv; s1 += v0; s2 += v0 * v0; }
#pragma unroll
        for (int off = 32; off > 0; off >>= 1) {
            s1 += __shfl_xor(s1, off);
            s2 += __shfl_xor(s2, off);
        }
        if (lane == 0) {
            double m = s1 / (double)NN;
            double var = (s2 - (double)NN * m * m) / (double)(NN - 1);
            mu[a] = (float)m;
            sd[a] = (float)sqrt(fmax(var, 0.0));
        }
    }
}

// ---------------- R[a][c] = exp((rwn[a][c]-mu[c])^2 / (2 sd[c]^2)) ----------------
__global__ void r_kernel(const float* __restrict__ rwn, const float* __restrict__ mu,
                         const float* __restrict__ sd, float* __restrict__ R) {
    int a = blockIdx.x, c = threadIdx.x;
    if (c < PP) {
        float d = rwn[a * PP + c] - mu[c];
        float s = sd[c];
        R[a * PP + c] = expf(d * d / (2.0f * s * s));
    }
}

// ---- Ctabp[p][c] = (c in neg_q[pi[p]]) ? R[hqp[p]][c] : 0  (128 rows/block) ----
__global__ __launch_bounds__(256) void ctab_kernel(
    const int* __restrict__ pi, const int* __restrict__ hqp, const int* __restrict__ nq,
    const float* __restrict__ R, float* __restrict__ Ctab) {
    const int p0 = blockIdx.x * 128;
    const int t = threadIdx.x;
    __shared__ unsigned long long bits[128][2];
    __shared__ int cls[128];
    if (t < 128) {
        const int p = p0 + t;
        const int* row = nq + (size_t)pi[p] * KK;
        unsigned long long b0 = 0, b1 = 0;
#pragma unroll
        for (int k = 0; k < KK; ++k) {
            int c = row[k];
            if (c < 64) b0 |= 1ull << c; else b1 |= 1ull << (c - 64);
        }
        bits[t][0] = b0;
        bits[t][1] = b1;
        cls[t] = hqp[p];
    }
    __syncthreads();
    for (int idx = t; idx < 128 * PP; idx += 256) {
        int pl = idx / PP;
        int c = idx - pl * PP;
        bool m = (c < 64) ? ((bits[pl][0] >> c) & 1) : ((bits[pl][1] >> (c - 64)) & 1);
        Ctab[(size_t)p0 * PP + idx] = m ? R[cls[pl] * PP + c] : 0.f;
    }
}

// ---------------- main fused GEMM: barrier-free, XCD-swizzled ----------
// denom = sum_{p!=q} exp(5*dot_pq) * Ctabp[p][hqp[q]]   (indices sorted by class)
// Block grid 4096 linear; region = L%8 -> XCD (L2 locality): each region is a
// 16(bi) x 32(bj) slab => per-XCD working set A 1MB + B 2MB + Ctab rows 0.8MB < 4MB L2.
__global__ __launch_bounds__(256) void sim_kernel(
    const _Float16* __restrict__ Gp, const int* __restrict__ hqp,
    const float* __restrict__ Ctabp, double* __restrict__ dpart) {
    const int L = blockIdx.x;        // 0..4095
    const int xcd = L & 7;
    const int s = L >> 3;            // 0..511
    const int bi = (xcd >> 1) * 16 + (s & 15);
    const int bj = (xcd & 1) * 32 + (s >> 4);

    const int t = threadIdx.x;
    const int lane = t & 63;
    const int wv = t >> 6;
    const int i0 = bi * 128 + (wv >> 1) * 64;
    const int j0 = bj * 128 + (wv & 1) * 64;

    f32x16 acc[2][2] = {};

    const _Float16* pa0 = Gp + (size_t)((i0 >> 5) + 0) * 16 * 512 + lane * 8;
    const _Float16* pa1 = Gp + (size_t)((i0 >> 5) + 1) * 16 * 512 + lane * 8;
    const _Float16* pb0 = Gp + (size_t)((j0 >> 5) + 0) * 16 * 512 + lane * 8;
    const _Float16* pb1 = Gp + (size_t)((j0 >> 5) + 1) * 16 * 512 + lane * 8;

#pragma unroll
    for (int kc = 0; kc < 16; ++kc) {
        f16x8 a0 = *(const f16x8*)(pa0 + kc * 512);
        f16x8 a1 = *(const f16x8*)(pa1 + kc * 512);
        f16x8 b0 = *(const f16x8*)(pb0 + kc * 512);
        f16x8 b1 = *(const f16x8*)(pb1 + kc * 512);
        acc[0][0] = __builtin_amdgcn_mfma_f32_32x32x16_f16(a0, b0, acc[0][0], 0, 0, 0);
        acc[0][1] = __builtin_amdgcn_mfma_f32_32x32x16_f16(a0, b1, acc[0][1], 0, 0, 0);
        acc[1][0] = __builtin_amdgcn_mfma_f32_32x32x16_f16(a1, b0, acc[1][0], 0, 0, 0);
        acc[1][1] = __builtin_amdgcn_mfma_f32_32x32x16_f16(a1, b1, acc[1][1], 0, 0, 0);
    }

    // C/D layout (32x32): col = lane&31, row = (reg&3) + 8*(reg>>2) + 4*(lane>>5)
    const int cl = lane & 31, h = lane >> 5;
    const int cls0 = hqp[j0 + cl];
    const int cls1 = hqp[j0 + 32 + cl];
    float partial = 0.f;
#pragma unroll
    for (int mi = 0; mi < 2; ++mi) {
        const int rb = i0 + mi * 32 + 4 * h;
#pragma unroll
        for (int ni = 0; ni < 2; ++ni) {
            const int cls = ni ? cls1 : cls0;
            const int col = j0 + ni * 32 + cl;
#pragma unroll
            for (int r = 0; r < 16; ++r) {
                const int row = rb + (r & 3) + 8 * (r >> 2);
                const float coef = Ctabp[(size_t)row * PP + cls];
                const float e = __expf(acc[mi][ni][r] * 5.0f);
                partial += (row != col) ? e * coef : 0.f;
            }
        }
    }
#pragma unroll
    for (int off = 32; off > 0; off >>= 1) partial += __shfl_down(partial, off);
    __shared__ float wsum[4];
    if (lane == 0) wsum[wv] = partial;
    __syncthreads();
    if (t == 0)
        atomicAdd(&dpart[L & 63], (double)(wsum[0] + wsum[1] + wsum[2] + wsum[3]));
}

// ---------------- finalize ----------------
__global__ void finalize_kernel(const double* __restrict__ dpart,
                                const double* __restrict__ ppart, float* __restrict__ out) {
    const int lane = threadIdx.x;  // 64
    double d = dpart[lane], p = ppart[lane];
#pragma unroll
    for (int off = 32; off > 0; off >>= 1) {
        d += __shfl_down(d, off);
        p += __shfl_down(p, off);
    }
    if (lane == 0) out[0] = (float)(log(d) - p * (5.0 / 4096.0));
}

extern "C" void kernel_launch(void* const* d_in, const int* in_sizes, int n_in,
                              void* d_out, int out_size, void* d_ws, size_t ws_size,
                              hipStream_t stream) {
    const float* x  = (const float*)d_in[0];
    const float* xa = (const float*)d_in[1];
    const float* pw = (const float*)d_in[2];
    const int* hq   = (const int*)d_in[3];
    const int* nq   = (const int*)d_in[4];
    float* out      = (float*)d_out;

    char* ws = (char*)d_ws;
    double* dpart = (double*)(ws + OFF_DPART);
    double* ppart = (double*)(ws + OFF_PPART);
    int* cnt      = (int*)(ws + OFF_CNT);
    float* mu     = (float*)(ws + OFF_MU);
    float* sd     = (float*)(ws + OFF_SD);
    float* rwn    = (float*)(ws + OFF_RWN);
    float* R      = (float*)(ws + OFF_R);
    int* pi       = (int*)(ws + OFF_PI);
    int* invp     = (int*)(ws + OFF_INVP);
    int* hqp      = (int*)(ws + OFF_HQP);
    float* Ctabp  = (float*)(ws + OFF_CTAB);
    _Float16* Gp  = (_Float16*)(ws + OFF_G);

    sortprep_kernel<<<1, 256, 0, stream>>>(hq, cnt, pi, invp, hqp, dpart, ppart);
    normalize_kernel<<<BB, DD, 0, stream>>>(x, xa, invp, Gp, ppart);
    pdstats_kernel<<<PP, 128, 0, stream>>>(pw, cnt, rwn, mu, sd);
    r_kernel<<<PP, 128, 0, stream>>>(rwn, mu, sd, R);
    ctab_kernel<<<NN / 128, 256, 0, stream>>>(pi, hqp, nq, R, Ctabp);
    sim_kernel<<<4096, 256, 0, stream>>>(Gp, hqp, Ctabp, dpart);
    finalize_kernel<<<1, 64, 0, stream>>>(dpart, ppart, out);
}

// Round 5
// 208.997 us; speedup vs baseline: 1.2245x; 1.2245x over previous
//
#include <hip/hip_runtime.h>
#include <cmath>

// Problem constants (B=4096, D=256, P=100, K=10, n=2B=8192, T=0.2)
#define BB   4096
#define DD   256
#define NN   8192
#define PP   100
#define KK   10

typedef float f32x16 __attribute__((ext_vector_type(16)));

// ---------------- workspace layout (bytes) ----------------
constexpr size_t OFF_DPART = 0;        // 64 double
constexpr size_t OFF_PPART = 512;      // 64 double
constexpr size_t OFF_CNT   = 1024;     // 100 int
constexpr size_t OFF_SO    = 1536;     // 100 int (scatter cursors)
constexpr size_t OFF_MU    = 2048;     // 100 f32
constexpr size_t OFF_SD    = 2560;     // 100 f32
constexpr size_t OFF_RWN   = 3072;     // 10000 f32 -> 43072
constexpr size_t OFF_R     = 43072;    // 10000 f32 -> 83072
constexpr size_t OFF_PI    = 83072;    // 8192 int (sorted pos -> orig)
constexpr size_t OFF_INVP  = 115840;   // 8192 int (orig -> sorted pos)
constexpr size_t OFF_HQP   = 148608;   // 8192 int (class at sorted pos)
constexpr size_t OFF_CTAB  = 181376;   // 8192*100 f32 -> 3458176
constexpr size_t OFF_WN    = 3458176;  // 100*256 f32 -> 3560576
constexpr size_t OFF_G     = 3560576;  // 8192*256 fp8 (2 MB), 16B aligned

// Fragment-packed fp8 G layout for mfma_f32_32x32x16_fp8_fp8 (byte addr):
// element (row p, k) at ((p>>5)*16 + (k>>4))*512 + ((k>>3)&1)*256 + (p&31)*8 + (k&7)
// lane l's 8-byte A/B fragment for group g, kc: (g*16+kc)*512 + l*8.

// ---------------- init: zero cnt ----------------
__global__ void init_kernel(int* __restrict__ cnt) {
    if (threadIdx.x < PP) cnt[threadIdx.x] = 0;
}

// ---------------- parallel histogram ----------------
__global__ void hist_kernel(const int* __restrict__ hq, int* __restrict__ cnt) {
    int i = blockIdx.x * 256 + threadIdx.x;
    if (i < NN) atomicAdd(&cnt[hq[i]], 1);
}

// ---------------- scan (1 block): offsets + zero accumulators ----------------
__global__ void scan_kernel(const int* __restrict__ cnt, int* __restrict__ so,
                            double* __restrict__ dpart, double* __restrict__ ppart) {
    const int t = threadIdx.x;
    if (t < 64) { dpart[t] = 0.0; ppart[t] = 0.0; }
    if (t == 0) {
        int run = 0;
        for (int c = 0; c < PP; ++c) { so[c] = run; run += cnt[c]; }
    }
}

// ---------------- parallel counting-sort scatter (any in-class order OK) ------
__global__ void scatter_kernel(const int* __restrict__ hq, int* __restrict__ so,
                               int* __restrict__ pi, int* __restrict__ invp,
                               int* __restrict__ hqp) {
    int i = blockIdx.x * 256 + threadIdx.x;
    if (i < NN) {
        int c = hq[i];
        int d = atomicAdd(&so[c], 1);
        pi[d] = i;
        invp[i] = d;
        hqp[d] = c;
    }
}

// ---------------- normalize rows -> fp8 fragment-packed Gp, pos dot ----------
__global__ void normalize_kernel(const float* __restrict__ x, const float* __restrict__ xa,
                                 const int* __restrict__ invp,
                                 char* __restrict__ Gpb, double* __restrict__ ppart) {
    const int i = blockIdx.x;       // 0..4095 (source row)
    const int t = threadIdx.x;      // 0..255 == D
    float v1 = x[(size_t)i * DD + t];
    float v2 = xa[(size_t)i * DD + t];
    float a = v1 * v1, b = v2 * v2, c = v1 * v2;
#pragma unroll
    for (int off = 32; off > 0; off >>= 1) {
        a += __shfl_down(a, off);
        b += __shfl_down(b, off);
        c += __shfl_down(c, off);
    }
    __shared__ float sa[4], sb[4], sc[4];
    __shared__ float sn[2][DD];
    const int lane = t & 63, wv = t >> 6;
    if (lane == 0) { sa[wv] = a; sb[wv] = b; sc[wv] = c; }
    __syncthreads();
    float ta = sa[0] + sa[1] + sa[2] + sa[3];
    float tb = sb[0] + sb[1] + sb[2] + sb[3];
    float tc = sc[0] + sc[1] + sc[2] + sc[3];
    float d1 = fmaxf(sqrtf(ta), 1e-12f);
    float d2 = fmaxf(sqrtf(tb), 1e-12f);
    sn[0][t] = v1 / d1;
    sn[1][t] = v2 / d2;
    __syncthreads();
    if (t < 64) {
        const int r = t >> 5;          // 0: row p1, 1: row p2
        const int cch = t & 31;        // chunk 0..31
        const int kc = cch >> 1, half = cch & 1;
        const int kb = kc * 16 + half * 8;
        const float* src = sn[r];
        int w0 = __builtin_amdgcn_cvt_pk_fp8_f32(src[kb + 0], src[kb + 1], 0, false);
        w0 = __builtin_amdgcn_cvt_pk_fp8_f32(src[kb + 2], src[kb + 3], w0, true);
        int w1 = __builtin_amdgcn_cvt_pk_fp8_f32(src[kb + 4], src[kb + 5], 0, false);
        w1 = __builtin_amdgcn_cvt_pk_fp8_f32(src[kb + 6], src[kb + 7], w1, true);
        const int p = r ? invp[i + BB] : invp[i];
        const size_t addr = (size_t)(((p >> 5) * 16 + kc) * 512 + half * 256 + (p & 31) * 8);
        *(int2*)(Gpb + addr) = make_int2(w0, w1);
    }
    if (t == 0) atomicAdd(&ppart[i & 63], (double)(tc / (d1 * d2)));
}

// ---------------- normalize prototype rows -> wn[100][256] f32 ----------------
__global__ void proto_norm_kernel(const float* __restrict__ pw, float* __restrict__ wn) {
    const int r = blockIdx.x;   // 0..99
    const int t = threadIdx.x;  // 0..255
    float v = pw[(size_t)r * DD + t];
    float a = v * v;
#pragma unroll
    for (int off = 32; off > 0; off >>= 1) a += __shfl_down(a, off);
    __shared__ float sa[4];
    const int lane = t & 63, wv = t >> 6;
    if (lane == 0) sa[wv] = a;
    __syncthreads();
    float ta = sa[0] + sa[1] + sa[2] + sa[3];
    float d = fmaxf(sqrtf(ta), 1e-12f);
    wn[(size_t)r * DD + t] = v / d;
}

// ---------------- pd row + per-class stats (parallel dots, R3 structure) -------
__global__ void pdstats_kernel(const float* __restrict__ wn, const int* __restrict__ cnt,
                               float* __restrict__ rwn, float* __restrict__ mu,
                               float* __restrict__ sd) {
    const int a = blockIdx.x;   // 0..99
    const int t = threadIdx.x;  // 0..127
    __shared__ float wb[DD];
    __shared__ float pdrow[PP];
    wb[t] = wn[(size_t)a * DD + t];
    wb[t + 128] = wn[(size_t)a * DD + t + 128];
    __syncthreads();
    if (t < PP) {
        const float* wc = wn + (size_t)t * DD;
        float dot = 0.f;
        for (int k = 0; k < DD; ++k) dot += wb[k] * wc[k];
        pdrow[t] = 1.0f - dot;
    }
    __syncthreads();
    if (t < 64) {
        const int lane = t;
        float vmin = 0.f, vmax = 0.f;  // eye-zero always in multiset
        for (int b = lane; b < PP; b += 64) {
            int cc = cnt[b] - (b == a ? 1 : 0);
            if (cc > 0) {
                float v = pdrow[b];
                vmin = fminf(vmin, v);
                vmax = fmaxf(vmax, v);
            }
        }
#pragma unroll
        for (int off = 32; off > 0; off >>= 1) {
            vmin = fminf(vmin, __shfl_xor(vmin, off));
            vmax = fmaxf(vmax, __shfl_xor(vmax, off));
        }
        const float den = vmax - vmin;
        const float inv = (den > 0.f) ? 1.f / den : 0.f;
        double s1 = 0.0, s2 = 0.0;
        for (int b = lane; b < PP; b += 64) {
            float v = (pdrow[b] - vmin) * inv;
            rwn[a * PP + b] = v;
            int cc = cnt[b] - (b == a ? 1 : 0);
            if (cc > 0) { double dv = v; s1 += cc * dv; s2 += cc * dv * dv; }
        }
        if (lane == 0) { double v0 = (0.0 - (double)vmin) * inv; s1 += v0; s2 += v0 * v0; }
#pragma unroll
        for (int off = 32; off > 0; off >>= 1) {
            s1 += __shfl_xor(s1, off);
            s2 += __shfl_xor(s2, off);
        }
        if (lane == 0) {
            double m = s1 / (double)NN;
            double var = (s2 - (double)NN * m * m) / (double)(NN - 1);
            mu[a] = (float)m;
            sd[a] = (float)sqrt(fmax(var, 0.0));
        }
    }
}

// ---------------- R[a][c] = exp((rwn[a][c]-mu[c])^2 / (2 sd[c]^2)) ----------------
__global__ void r_kernel(const float* __restrict__ rwn, const float* __restrict__ mu,
                         const float* __restrict__ sd, float* __restrict__ R) {
    int a = blockIdx.x, c = threadIdx.x;
    if (c < PP) {
        float d = rwn[a * PP + c] - mu[c];
        float s = sd[c];
        R[a * PP + c] = expf(d * d / (2.0f * s * s));
    }
}

// ---- Ctabp[p][c] = (c in neg_q[pi[p]]) ? R[hqp[p]][c] : 0  (128 rows/block) ----
__global__ __launch_bounds__(256) void ctab_kernel(
    const int* __restrict__ pi, const int* __restrict__ hqp, const int* __restrict__ nq,
    const float* __restrict__ R, float* __restrict__ Ctab) {
    const int p0 = blockIdx.x * 128;
    const int t = threadIdx.x;
    __shared__ unsigned long long bits[128][2];
    __shared__ int cls[128];
    if (t < 128) {
        const int p = p0 + t;
        const int* row = nq + (size_t)pi[p] * KK;
        unsigned long long b0 = 0, b1 = 0;
#pragma unroll
        for (int k = 0; k < KK; ++k) {
            int c = row[k];
            if (c < 64) b0 |= 1ull << c; else b1 |= 1ull << (c - 64);
        }
        bits[t][0] = b0;
        bits[t][1] = b1;
        cls[t] = hqp[p];
    }
    __syncthreads();
    for (int idx = t; idx < 128 * PP; idx += 256) {
        int pl = idx / PP;
        int c = idx - pl * PP;
        bool m = (c < 64) ? ((bits[pl][0] >> c) & 1) : ((bits[pl][1] >> (c - 64)) & 1);
        Ctab[(size_t)p0 * PP + idx] = m ? R[cls[pl] * PP + c] : 0.f;
    }
}

// ---------------- main fused GEMM: fp8 fragments, barrier-free, XCD-swizzled ----
// denom = sum_{p!=q} exp(5*dot_pq) * Ctabp[p][hqp[q]]   (indices sorted by class)
__global__ __launch_bounds__(256) void sim_kernel(
    const char* __restrict__ Gpb, const int* __restrict__ hqp,
    const float* __restrict__ Ctabp, double* __restrict__ dpart) {
    const int L = blockIdx.x;        // 0..4095
    const int xcd = L & 7;
    const int s = L >> 3;            // 0..511
    const int bi = (xcd >> 1) * 16 + (s & 15);
    const int bj = (xcd & 1) * 32 + (s >> 4);

    const int t = threadIdx.x;
    const int lane = t & 63;
    const int wv = t >> 6;
    const int i0 = bi * 128 + (wv >> 1) * 64;
    const int j0 = bj * 128 + (wv & 1) * 64;

    f32x16 acc[2][2] = {};

    const char* pa0 = Gpb + (size_t)((i0 >> 5) + 0) * 16 * 512 + lane * 8;
    const char* pa1 = Gpb + (size_t)((i0 >> 5) + 1) * 16 * 512 + lane * 8;
    const char* pb0 = Gpb + (size_t)((j0 >> 5) + 0) * 16 * 512 + lane * 8;
    const char* pb1 = Gpb + (size_t)((j0 >> 5) + 1) * 16 * 512 + lane * 8;

#pragma unroll
    for (int kc = 0; kc < 16; ++kc) {
        long a0 = *(const long*)(pa0 + kc * 512);
        long a1 = *(const long*)(pa1 + kc * 512);
        long b0 = *(const long*)(pb0 + kc * 512);
        long b1 = *(const long*)(pb1 + kc * 512);
        acc[0][0] = __builtin_amdgcn_mfma_f32_32x32x16_fp8_fp8(a0, b0, acc[0][0], 0, 0, 0);
        acc[0][1] = __builtin_amdgcn_mfma_f32_32x32x16_fp8_fp8(a0, b1, acc[0][1], 0, 0, 0);
        acc[1][0] = __builtin_amdgcn_mfma_f32_32x32x16_fp8_fp8(a1, b0, acc[1][0], 0, 0, 0);
        acc[1][1] = __builtin_amdgcn_mfma_f32_32x32x16_fp8_fp8(a1, b1, acc[1][1], 0, 0, 0);
    }

    // C/D layout (32x32): col = lane&31, row = (reg&3) + 8*(reg>>2) + 4*(lane>>5)
    const int cl = lane & 31, h = lane >> 5;
    const int cls0 = hqp[j0 + cl];
    const int cls1 = hqp[j0 + 32 + cl];
    float partial = 0.f;
#pragma unroll
    for (int mi = 0; mi < 2; ++mi) {
        const int rb = i0 + mi * 32 + 4 * h;
#pragma unroll
        for (int ni = 0; ni < 2; ++ni) {
            const int cls = ni ? cls1 : cls0;
            const int col = j0 + ni * 32 + cl;
#pragma unroll
            for (int r = 0; r < 16; ++r) {
                const int row = rb + (r & 3) + 8 * (r >> 2);
                const float coef = Ctabp[(size_t)row * PP + cls];
                const float e = __expf(acc[mi][ni][r] * 5.0f);
                partial += (row != col) ? e * coef : 0.f;
            }
        }
    }
#pragma unroll
    for (int off = 32; off > 0; off >>= 1) partial += __shfl_down(partial, off);
    __shared__ float wsum[4];
    if (lane == 0) wsum[wv] = partial;
    __syncthreads();
    if (t == 0)
        atomicAdd(&dpart[L & 63], (double)(wsum[0] + wsum[1] + wsum[2] + wsum[3]));
}

// ---------------- finalize ----------------
__global__ void finalize_kernel(const double* __restrict__ dpart,
                                const double* __restrict__ ppart, float* __restrict__ out) {
    const int lane = threadIdx.x;  // 64
    double d = dpart[lane], p = ppart[lane];
#pragma unroll
    for (int off = 32; off > 0; off >>= 1) {
        d += __shfl_down(d, off);
        p += __shfl_down(p, off);
    }
    if (lane == 0) out[0] = (float)(log(d) - p * (5.0 / 4096.0));
}

extern "C" void kernel_launch(void* const* d_in, const int* in_sizes, int n_in,
                              void* d_out, int out_size, void* d_ws, size_t ws_size,
                              hipStream_t stream) {
    const float* x  = (const float*)d_in[0];
    const float* xa = (const float*)d_in[1];
    const float* pw = (const float*)d_in[2];
    const int* hq   = (const int*)d_in[3];
    const int* nq   = (const int*)d_in[4];
    float* out      = (float*)d_out;

    char* ws = (char*)d_ws;
    double* dpart = (double*)(ws + OFF_DPART);
    double* ppart = (double*)(ws + OFF_PPART);
    int* cnt      = (int*)(ws + OFF_CNT);
    int* so       = (int*)(ws + OFF_SO);
    float* mu     = (float*)(ws + OFF_MU);
    float* sd     = (float*)(ws + OFF_SD);
    float* rwn    = (float*)(ws + OFF_RWN);
    float* R      = (float*)(ws + OFF_R);
    int* pi       = (int*)(ws + OFF_PI);
    int* invp     = (int*)(ws + OFF_INVP);
    int* hqp      = (int*)(ws + OFF_HQP);
    float* Ctabp  = (float*)(ws + OFF_CTAB);
    float* wn     = (float*)(ws + OFF_WN);
    char* Gpb     = (char*)(ws + OFF_G);

    init_kernel<<<1, 128, 0, stream>>>(cnt);
    hist_kernel<<<NN / 256, 256, 0, stream>>>(hq, cnt);
    scan_kernel<<<1, 128, 0, stream>>>(cnt, so, dpart, ppart);
    scatter_kernel<<<NN / 256, 256, 0, stream>>>(hq, so, pi, invp, hqp);
    normalize_kernel<<<BB, DD, 0, stream>>>(x, xa, invp, Gpb, ppart);
    proto_norm_kernel<<<PP, DD, 0, stream>>>(pw, wn);
    pdstats_kernel<<<PP, 128, 0, stream>>>(wn, cnt, rwn, mu, sd);
    r_kernel<<<PP, 128, 0, stream>>>(rwn, mu, sd, R);
    ctab_kernel<<<NN / 128, 256, 0, stream>>>(pi, hqp, nq, R, Ctabp);
    sim_kernel<<<4096, 256, 0, stream>>>(Gpb, hqp, Ctabp, dpart);
    finalize_kernel<<<1, 64, 0, stream>>>(dpart, ppart, out);
}

// Round 6
// 183.134 us; speedup vs baseline: 1.3974x; 1.1412x over previous
//
#include <hip/hip_runtime.h>
#include <cmath>

// Problem constants (B=4096, D=256, P=100, K=10, n=2B=8192, T=0.2)
#define BB   4096
#define DD   256
#define NN   8192
#define PP   100
#define KK   10

typedef float f32x16 __attribute__((ext_vector_type(16)));

// ---------------- workspace layout (bytes) ----------------
constexpr size_t OFF_DPART = 0;        // 64 double
constexpr size_t OFF_PPART = 512;      // 64 double
constexpr size_t OFF_CNT   = 1024;     // 100 int
constexpr size_t OFF_SO    = 1536;     // 100 int (scatter cursors)
constexpr size_t OFF_MU    = 2048;     // 100 f32
constexpr size_t OFF_SD    = 2560;     // 100 f32
constexpr size_t OFF_RWN   = 3072;     // 10000 f32 -> 43072
constexpr size_t OFF_PI    = 43072;    // 8192 int (sorted pos -> orig)
constexpr size_t OFF_HQP   = 75840;    // 8192 int (class at sorted pos)
constexpr size_t OFF_CTABT = 108608;   // 100*8192 f32 transposed -> 3385408 (16B aligned)
constexpr size_t OFF_G     = 3385408;  // 8192*256 fp8 fragment-packed (2 MB), 16B aligned

// Fragment-packed fp8 G layout for mfma_f32_32x32x16_fp8_fp8 (byte addr):
// element (row p, k) at ((p>>5)*16 + (k>>4))*512 + ((k>>3)&1)*256 + (p&31)*8 + (k&7)

// ---------------- prep (1 block): zero accs, histogram, scan ----------------
__global__ __launch_bounds__(1024) void prep_kernel(
    const int* __restrict__ hq, int* __restrict__ cnt, int* __restrict__ so,
    double* __restrict__ dpart, double* __restrict__ ppart) {
    __shared__ int h[16][PP];
    __shared__ int sc[PP];
    const int t = threadIdx.x;   // 1024
    const int wv = t >> 6;
    h[t & 15][t >> 4] = 0;       // zero 16x100 <= 1600 slots: do 2 passes
    if (t < 576) h[(t + 1024) & 15][(t + 1024) >> 4] = 0;
    if (t < 64) { dpart[t] = 0.0; ppart[t] = 0.0; }
    __syncthreads();
#pragma unroll
    for (int r = 0; r < 8; ++r) {
        int i = r * 1024 + t;
        atomicAdd(&h[wv][hq[i]], 1);
    }
    __syncthreads();
    if (t < PP) {
        int s = 0;
#pragma unroll
        for (int w = 0; w < 16; ++w) s += h[w][t];
        cnt[t] = s;
        sc[t] = s;
    }
    __syncthreads();
    if (t == 0) {
        int run = 0;
        for (int c = 0; c < PP; ++c) { so[c] = run; run += sc[c]; }
    }
}

// ------- normalize rows -> fp8 fragment-packed Gp; fused sort-scatter; pos dot ----
__global__ void normalize_kernel(const float* __restrict__ x, const float* __restrict__ xa,
                                 const int* __restrict__ hq, int* __restrict__ so,
                                 int* __restrict__ pi, int* __restrict__ hqp,
                                 char* __restrict__ Gpb, double* __restrict__ ppart) {
    const int i = blockIdx.x;       // 0..4095 (source sample)
    const int t = threadIdx.x;      // 0..255 == D
    __shared__ int sp[2];
    if (t < 2) {                    // counting-sort scatter (any in-class order OK)
        const int idx = t ? i + BB : i;
        const int c = hq[idx];
        const int d = atomicAdd(&so[c], 1);
        pi[d] = idx;
        hqp[d] = c;
        sp[t] = d;
    }
    float v1 = x[(size_t)i * DD + t];
    float v2 = xa[(size_t)i * DD + t];
    float a = v1 * v1, b = v2 * v2, c = v1 * v2;
#pragma unroll
    for (int off = 32; off > 0; off >>= 1) {
        a += __shfl_down(a, off);
        b += __shfl_down(b, off);
        c += __shfl_down(c, off);
    }
    __shared__ float sa[4], sb[4], sc[4];
    __shared__ float sn[2][DD];
    const int lane = t & 63, wv = t >> 6;
    if (lane == 0) { sa[wv] = a; sb[wv] = b; sc[wv] = c; }
    __syncthreads();
    float ta = sa[0] + sa[1] + sa[2] + sa[3];
    float tb = sb[0] + sb[1] + sb[2] + sb[3];
    float tc = sc[0] + sc[1] + sc[2] + sc[3];
    float d1 = fmaxf(sqrtf(ta), 1e-12f);
    float d2 = fmaxf(sqrtf(tb), 1e-12f);
    sn[0][t] = v1 / d1;
    sn[1][t] = v2 / d2;
    __syncthreads();
    if (t < 64) {
        const int r = t >> 5;          // 0: view-1 row, 1: view-2 row
        const int cch = t & 31;        // chunk 0..31
        const int kc = cch >> 1, half = cch & 1;
        const int kb = kc * 16 + half * 8;
        const float* src = sn[r];
        int w0 = __builtin_amdgcn_cvt_pk_fp8_f32(src[kb + 0], src[kb + 1], 0, false);
        w0 = __builtin_amdgcn_cvt_pk_fp8_f32(src[kb + 2], src[kb + 3], w0, true);
        int w1 = __builtin_amdgcn_cvt_pk_fp8_f32(src[kb + 4], src[kb + 5], 0, false);
        w1 = __builtin_amdgcn_cvt_pk_fp8_f32(src[kb + 6], src[kb + 7], w1, true);
        const int p = sp[r];
        const size_t addr = (size_t)(((p >> 5) * 16 + kc) * 512 + half * 256 + (p & 31) * 8);
        *(int2*)(Gpb + addr) = make_int2(w0, w1);
    }
    if (t == 0) atomicAdd(&ppart[i & 63], (double)(tc / (d1 * d2)));
}

// -------- fused: proto-norm row a + pd row + per-class stats (no in-loop barriers) ----
__global__ void protopd_kernel(const float* __restrict__ pw, const int* __restrict__ cnt,
                               float* __restrict__ rwn, float* __restrict__ mu,
                               float* __restrict__ sd) {
    const int a = blockIdx.x;   // 0..99
    const int t = threadIdx.x;  // 0..255
    __shared__ float wa[DD];
    __shared__ float pdrow[PP];
    __shared__ float r4[4];
    float av = pw[(size_t)a * DD + t];
    float ss = av * av;
#pragma unroll
    for (int off = 32; off > 0; off >>= 1) ss += __shfl_down(ss, off);
    if ((t & 63) == 0) r4[t >> 6] = ss;
    __syncthreads();
    float na = fmaxf(sqrtf(r4[0] + r4[1] + r4[2] + r4[3]), 1e-12f);
    wa[t] = av / na;
    __syncthreads();
    if (t < PP) {
        const float* wc = pw + (size_t)t * DD;
        float dot = 0.f, nb = 0.f;
        for (int k = 0; k < DD; ++k) {
            float w = wc[k];
            dot += wa[k] * w;
            nb += w * w;
        }
        pdrow[t] = 1.0f - dot / fmaxf(sqrtf(nb), 1e-12f);
    }
    __syncthreads();
    if (t < 64) {
        const int lane = t;
        float vmin = 0.f, vmax = 0.f;  // eye-zero always in multiset
        for (int b = lane; b < PP; b += 64) {
            int cc = cnt[b] - (b == a ? 1 : 0);
            if (cc > 0) {
                float v = pdrow[b];
                vmin = fminf(vmin, v);
                vmax = fmaxf(vmax, v);
            }
        }
#pragma unroll
        for (int off = 32; off > 0; off >>= 1) {
            vmin = fminf(vmin, __shfl_xor(vmin, off));
            vmax = fmaxf(vmax, __shfl_xor(vmax, off));
        }
        const float den = vmax - vmin;
        const float inv = (den > 0.f) ? 1.f / den : 0.f;
        double s1 = 0.0, s2 = 0.0;
        for (int b = lane; b < PP; b += 64) {
            float v = (pdrow[b] - vmin) * inv;
            rwn[a * PP + b] = v;
            int cc = cnt[b] - (b == a ? 1 : 0);
            if (cc > 0) { double dv = v; s1 += cc * dv; s2 += cc * dv * dv; }
        }
        if (lane == 0) { double v0 = (0.0 - (double)vmin) * inv; s1 += v0; s2 += v0 * v0; }
#pragma unroll
        for (int off = 32; off > 0; off >>= 1) {
            s1 += __shfl_xor(s1, off);
            s2 += __shfl_xor(s2, off);
        }
        if (lane == 0) {
            double m = s1 / (double)NN;
            double var = (s2 - (double)NN * m * m) / (double)(NN - 1);
            mu[a] = (float)m;
            sd[a] = (float)sqrt(fmax(var, 0.0));
        }
    }
}

// ---- CtabT[c][p] = (c in neg_q[pi[p]]) ? exp((rwn[hqp[p]][c]-mu[c])^2/(2 sd[c]^2)) : 0
__global__ __launch_bounds__(256) void ctab_kernel(
    const int* __restrict__ pi, const int* __restrict__ hqp, const int* __restrict__ nq,
    const float* __restrict__ rwn, const float* __restrict__ mu, const float* __restrict__ sd,
    float* __restrict__ CtabT) {
    const int p0 = blockIdx.x * 128;
    const int t = threadIdx.x;
    __shared__ unsigned long long bits[128][2];
    __shared__ int cls[128];
    __shared__ float smu[PP], ssd[PP];
    if (t < 128) {
        const int p = p0 + t;
        const int* row = nq + (size_t)pi[p] * KK;
        unsigned long long b0 = 0, b1 = 0;
#pragma unroll
        for (int k = 0; k < KK; ++k) {
            int c = row[k];
            if (c < 64) b0 |= 1ull << c; else b1 |= 1ull << (c - 64);
        }
        bits[t][0] = b0;
        bits[t][1] = b1;
        cls[t] = hqp[p];
    }
    if (t < PP) { smu[t] = mu[t]; ssd[t] = sd[t]; }
    __syncthreads();
    for (int idx = t; idx < 128 * PP; idx += 256) {
        const int c = idx >> 7;
        const int pl = idx & 127;
        const bool m = (c < 64) ? ((bits[pl][0] >> c) & 1) : ((bits[pl][1] >> (c - 64)) & 1);
        float v = 0.f;
        if (m) {
            float d = rwn[cls[pl] * PP + c] - smu[c];
            float s = ssd[c];
            v = expf(d * d / (2.0f * s * s));
        }
        CtabT[(size_t)c * NN + p0 + pl] = v;
    }
}

// ---------------- main fused GEMM: fp8, 32x64 wave tiles, vectorized coef ----------
// denom = sum_{p!=q} exp(5*dot_pq) * C[p][hqp[q]]   (indices sorted by class)
// Block: 4 waves, tile 128(i) x 64(j); wave w: rows i0w..i0w+31, all 64 cols.
// Grid 8192: xcd = L&7 -> (2 bi-halves x 4 bj-quarters); per-XCD L2 slab:
// A 1MB + B 0.5MB + CtabT rows ~0.8MB < 4MB.
__global__ __launch_bounds__(256) void sim_kernel(
    const char* __restrict__ Gpb, const int* __restrict__ hqp,
    const float* __restrict__ CtabT, double* __restrict__ dpart) {
    const int L = blockIdx.x;        // 0..8191
    const int xcd = L & 7;
    const int s = L >> 3;            // 0..1023
    const int bi = (xcd & 1) * 32 + (s & 31);    // 0..63   (128-row blocks)
    const int bj = (xcd >> 1) * 32 + (s >> 5);   // 0..127  (64-col blocks)

    const int t = threadIdx.x;
    const int lane = t & 63;
    const int wv = t >> 6;
    const int i0w = bi * 128 + wv * 32;   // this wave's 32-row group base
    const int j0 = bj * 64;

    f32x16 acc[2] = {};

    const char* pa  = Gpb + (size_t)(i0w >> 5) * 8192 + lane * 8;      // 16 kc * 512B
    const char* pb0 = Gpb + (size_t)(j0 >> 5) * 8192 + lane * 8;
    const char* pb1 = pb0 + 8192;

#pragma unroll
    for (int kc = 0; kc < 16; ++kc) {
        long a  = *(const long*)(pa  + kc * 512);
        long b0 = *(const long*)(pb0 + kc * 512);
        long b1 = *(const long*)(pb1 + kc * 512);
        acc[0] = __builtin_amdgcn_mfma_f32_32x32x16_fp8_fp8(a, b0, acc[0], 0, 0, 0);
        acc[1] = __builtin_amdgcn_mfma_f32_32x32x16_fp8_fp8(a, b1, acc[1], 0, 0, 0);
    }

    // C/D layout (32x32): col = lane&31, row = (reg&3) + 8*(reg>>2) + 4*(lane>>5)
    const int cl = lane & 31, h = lane >> 5;
    const int cls0 = hqp[j0 + cl];
    const int cls1 = hqp[j0 + 32 + cl];
    const float* ct0 = CtabT + (size_t)cls0 * NN;
    const float* ct1 = CtabT + (size_t)cls1 * NN;
    float partial = 0.f;
#pragma unroll
    for (int ni = 0; ni < 2; ++ni) {
        const float* ct = ni ? ct1 : ct0;
        const int col = j0 + ni * 32 + cl;
        const f32x16 av = acc[ni];
#pragma unroll
        for (int g = 0; g < 4; ++g) {
            const int rbase = i0w + 8 * g + 4 * h;
            const float4 cf = *(const float4*)(ct + rbase);   // 4 consecutive rows
            float e0 = __expf(av[4 * g + 0] * 5.0f);
            float e1 = __expf(av[4 * g + 1] * 5.0f);
            float e2 = __expf(av[4 * g + 2] * 5.0f);
            float e3 = __expf(av[4 * g + 3] * 5.0f);
            partial += (rbase + 0 != col) ? e0 * cf.x : 0.f;
            partial += (rbase + 1 != col) ? e1 * cf.y : 0.f;
            partial += (rbase + 2 != col) ? e2 * cf.z : 0.f;
            partial += (rbase + 3 != col) ? e3 * cf.w : 0.f;
        }
    }
#pragma unroll
    for (int off = 32; off > 0; off >>= 1) partial += __shfl_down(partial, off);
    __shared__ float wsum[4];
    if (lane == 0) wsum[wv] = partial;
    __syncthreads();
    if (t == 0)
        atomicAdd(&dpart[L & 63], (double)(wsum[0] + wsum[1] + wsum[2] + wsum[3]));
}

// ---------------- finalize ----------------
__global__ void finalize_kernel(const double* __restrict__ dpart,
                                const double* __restrict__ ppart, float* __restrict__ out) {
    const int lane = threadIdx.x;  // 64
    double d = dpart[lane], p = ppart[lane];
#pragma unroll
    for (int off = 32; off > 0; off >>= 1) {
        d += __shfl_down(d, off);
        p += __shfl_down(p, off);
    }
    if (lane == 0) out[0] = (float)(log(d) - p * (5.0 / 4096.0));
}

extern "C" void kernel_launch(void* const* d_in, const int* in_sizes, int n_in,
                              void* d_out, int out_size, void* d_ws, size_t ws_size,
                              hipStream_t stream) {
    const float* x  = (const float*)d_in[0];
    const float* xa = (const float*)d_in[1];
    const float* pw = (const float*)d_in[2];
    const int* hq   = (const int*)d_in[3];
    const int* nq   = (const int*)d_in[4];
    float* out      = (float*)d_out;

    char* ws = (char*)d_ws;
    double* dpart = (double*)(ws + OFF_DPART);
    double* ppart = (double*)(ws + OFF_PPART);
    int* cnt      = (int*)(ws + OFF_CNT);
    int* so       = (int*)(ws + OFF_SO);
    float* mu     = (float*)(ws + OFF_MU);
    float* sd     = (float*)(ws + OFF_SD);
    float* rwn    = (float*)(ws + OFF_RWN);
    int* pi       = (int*)(ws + OFF_PI);
    int* hqp      = (int*)(ws + OFF_HQP);
    float* CtabT  = (float*)(ws + OFF_CTABT);
    char* Gpb     = (char*)(ws + OFF_G);

    prep_kernel<<<1, 1024, 0, stream>>>(hq, cnt, so, dpart, ppart);
    normalize_kernel<<<BB, DD, 0, stream>>>(x, xa, hq, so, pi, hqp, Gpb, ppart);
    protopd_kernel<<<PP, 256, 0, stream>>>(pw, cnt, rwn, mu, sd);
    ctab_kernel<<<NN / 128, 256, 0, stream>>>(pi, hqp, nq, rwn, mu, sd, CtabT);
    sim_kernel<<<8192, 256, 0, stream>>>(Gpb, hqp, CtabT, dpart);
    finalize_kernel<<<1, 64, 0, stream>>>(dpart, ppart, out);
}

// Round 7
// 172.842 us; speedup vs baseline: 1.4806x; 1.0595x over previous
//
#include <hip/hip_runtime.h>
#include <cmath>

// Problem constants (B=4096, D=256, P=100, K=10, n=2B=8192, T=0.2)
#define BB   4096
#define DD   256
#define NN   8192
#define PP   100
#define KK   10

typedef float f32x16 __attribute__((ext_vector_type(16)));

// ---------------- workspace layout (bytes) ----------------
constexpr size_t OFF_DPART = 0;        // 64 double
constexpr size_t OFF_PPART = 512;      // 64 double
constexpr size_t OFF_CNT   = 1024;     // 100 int (pad to 512)
constexpr size_t OFF_MU    = 1536;     // 100 f32
constexpr size_t OFF_SD    = 2048;     // 100 f32
constexpr size_t OFF_RWN   = 2560;     // 10000 f32 -> 42560
constexpr size_t OFF_PI    = 42560;    // 8192 int (sorted pos -> orig)
constexpr size_t OFF_INVP  = 75328;    // 8192 int (orig -> sorted pos)
constexpr size_t OFF_HQP   = 108096;   // 8192 int (class at sorted pos)
constexpr size_t OFF_CTABT = 140864;   // 100*8192 f32 transposed -> 3417664 (16B aligned)
constexpr size_t OFF_G     = 3417664;  // 8192*256 fp8 fragment-packed (2 MB), 16B aligned

// Fragment-packed fp8 G layout for mfma_f32_32x32x16_fp8_fp8 (byte addr):
// element (row p, k) at ((p>>5)*16 + (k>>4))*512 + ((k>>3)&1)*256 + (p&31)*8 + (k&7)

// ------ prep (1 block): zero accs, LDS histogram, scan, full counting sort ------
__global__ __launch_bounds__(1024) void prep_kernel(
    const int* __restrict__ hq, int* __restrict__ cnt,
    int* __restrict__ pi, int* __restrict__ invp, int* __restrict__ hqp,
    double* __restrict__ dpart, double* __restrict__ ppart) {
    __shared__ int h[16][PP];
    __shared__ int cur[PP];
    const int t = threadIdx.x;   // 1024
    const int wv = t >> 6;
    h[t & 15][t >> 4] = 0;       // zero 16x100 = 1600 slots in 2 passes
    if (t < 576) h[(t + 1024) & 15][(t + 1024) >> 4] = 0;
    if (t < 64) { dpart[t] = 0.0; ppart[t] = 0.0; }
    __syncthreads();
#pragma unroll
    for (int r = 0; r < 8; ++r) atomicAdd(&h[wv][hq[r * 1024 + t]], 1);
    __syncthreads();
    if (t < PP) {
        int s = 0;
#pragma unroll
        for (int w = 0; w < 16; ++w) s += h[w][t];
        cnt[t] = s;
        h[0][t] = s;
    }
    __syncthreads();
    if (t == 0) {
        int run = 0;
        for (int c = 0; c < PP; ++c) { cur[c] = run; run += h[0][c]; }
    }
    __syncthreads();
#pragma unroll
    for (int r = 0; r < 8; ++r) {
        const int i = r * 1024 + t;
        const int c = hq[i];
        const int d = atomicAdd(&cur[c], 1);   // LDS atomic: fast
        pi[d] = i;
        hqp[d] = c;
        invp[i] = d;
    }
}

// ---- normalize: wave-per-sample, barrier-free -> fp8 fragment-packed Gp; pos dot ----
__global__ __launch_bounds__(256) void normalize_kernel(
    const float* __restrict__ x, const float* __restrict__ xa,
    const int* __restrict__ invp, char* __restrict__ Gpb, double* __restrict__ ppart) {
    const int wv = threadIdx.x >> 6, lane = threadIdx.x & 63;
    const int i = blockIdx.x * 4 + wv;            // sample 0..4095
    const float4 v1 = *(const float4*)(x  + (size_t)i * DD + lane * 4);
    const float4 v2 = *(const float4*)(xa + (size_t)i * DD + lane * 4);
    float a = v1.x * v1.x + v1.y * v1.y + v1.z * v1.z + v1.w * v1.w;
    float b = v2.x * v2.x + v2.y * v2.y + v2.z * v2.z + v2.w * v2.w;
    float c = v1.x * v2.x + v1.y * v2.y + v1.z * v2.z + v1.w * v2.w;
#pragma unroll
    for (int off = 32; off > 0; off >>= 1) {
        a += __shfl_xor(a, off);
        b += __shfl_xor(b, off);
        c += __shfl_xor(c, off);
    }
    const float d1 = fmaxf(sqrtf(a), 1e-12f), i1 = 1.0f / d1;
    const float d2 = fmaxf(sqrtf(b), 1e-12f), i2 = 1.0f / d2;
    const int p1 = invp[i];
    const int p2 = invp[i + BB];
    int w1 = __builtin_amdgcn_cvt_pk_fp8_f32(v1.x * i1, v1.y * i1, 0, false);
    w1 = __builtin_amdgcn_cvt_pk_fp8_f32(v1.z * i1, v1.w * i1, w1, true);
    int w2 = __builtin_amdgcn_cvt_pk_fp8_f32(v2.x * i2, v2.y * i2, 0, false);
    w2 = __builtin_amdgcn_cvt_pk_fp8_f32(v2.z * i2, v2.w * i2, w2, true);
    // lane l holds k in [4l,4l+4): kc=l>>2, half=(l>>1)&1, byte off 4*(l&1)
    const int kc = lane >> 2, half = (lane >> 1) & 1, bo = 4 * (lane & 1);
    const size_t a1 = (size_t)(((p1 >> 5) * 16 + kc) * 512 + half * 256 + (p1 & 31) * 8 + bo);
    const size_t a2 = (size_t)(((p2 >> 5) * 16 + kc) * 512 + half * 256 + (p2 & 31) * 8 + bo);
    *(int*)(Gpb + a1) = w1;
    *(int*)(Gpb + a2) = w2;
    if (lane == 0) atomicAdd(&ppart[i & 63], (double)(c * i1 * i2));
}

// -------- fused: proto-norm row a + pd row (float4 dots) + per-class stats --------
__global__ __launch_bounds__(256) void protopd_kernel(
    const float* __restrict__ pw, const int* __restrict__ cnt,
    float* __restrict__ rwn, float* __restrict__ mu, float* __restrict__ sd) {
    const int a = blockIdx.x;   // 0..99
    const int t = threadIdx.x;  // 0..255
    __shared__ alignas(16) float wa[DD];
    __shared__ float pdrow[PP];
    __shared__ float r4[4];
    float av = pw[(size_t)a * DD + t];
    float ss = av * av;
#pragma unroll
    for (int off = 32; off > 0; off >>= 1) ss += __shfl_down(ss, off);
    if ((t & 63) == 0) r4[t >> 6] = ss;
    __syncthreads();
    const float na = fmaxf(sqrtf(r4[0] + r4[1] + r4[2] + r4[3]), 1e-12f);
    wa[t] = av / na;
    __syncthreads();
    if (t < PP) {
        const float4* wc = (const float4*)(pw + (size_t)t * DD);
        float dot = 0.f, nb = 0.f;
#pragma unroll 4
        for (int k = 0; k < 64; ++k) {
            const float4 w = wc[k];
            const float4 u = *(const float4*)(wa + 4 * k);
            dot += u.x * w.x + u.y * w.y + u.z * w.z + u.w * w.w;
            nb += w.x * w.x + w.y * w.y + w.z * w.z + w.w * w.w;
        }
        pdrow[t] = 1.0f - dot / fmaxf(sqrtf(nb), 1e-12f);
    }
    __syncthreads();
    if (t < 64) {
        const int lane = t;
        float vmin = 0.f, vmax = 0.f;  // eye-zero always in multiset
        for (int b = lane; b < PP; b += 64) {
            int cc = cnt[b] - (b == a ? 1 : 0);
            if (cc > 0) {
                float v = pdrow[b];
                vmin = fminf(vmin, v);
                vmax = fmaxf(vmax, v);
            }
        }
#pragma unroll
        for (int off = 32; off > 0; off >>= 1) {
            vmin = fminf(vmin, __shfl_xor(vmin, off));
            vmax = fmaxf(vmax, __shfl_xor(vmax, off));
        }
        const float den = vmax - vmin;
        const float inv = (den > 0.f) ? 1.f / den : 0.f;
        double s1 = 0.0, s2 = 0.0;
        for (int b = lane; b < PP; b += 64) {
            float v = (pdrow[b] - vmin) * inv;
            rwn[a * PP + b] = v;
            int cc = cnt[b] - (b == a ? 1 : 0);
            if (cc > 0) { double dv = v; s1 += cc * dv; s2 += cc * dv * dv; }
        }
        if (lane == 0) { double v0 = (0.0 - (double)vmin) * inv; s1 += v0; s2 += v0 * v0; }
#pragma unroll
        for (int off = 32; off > 0; off >>= 1) {
            s1 += __shfl_xor(s1, off);
            s2 += __shfl_xor(s2, off);
        }
        if (lane == 0) {
            double m = s1 / (double)NN;
            double var = (s2 - (double)NN * m * m) / (double)(NN - 1);
            mu[a] = (float)m;
            sd[a] = (float)sqrt(fmax(var, 0.0));
        }
    }
}

// ---- CtabT[c][p] = (c in neg_q[pi[p]]) ? exp((rwn[hqp[p]][c]-mu[c])^2/(2 sd[c]^2)) : 0
__global__ __launch_bounds__(256) void ctab_kernel(
    const int* __restrict__ pi, const int* __restrict__ hqp, const int* __restrict__ nq,
    const float* __restrict__ rwn, const float* __restrict__ mu, const float* __restrict__ sd,
    float* __restrict__ CtabT) {
    const int p0 = blockIdx.x * 128;
    const int t = threadIdx.x;
    __shared__ unsigned long long bits[128][2];
    __shared__ int cls[128];
    __shared__ float smu[PP], ssd[PP];
    if (t < 128) {
        const int p = p0 + t;
        const int* row = nq + (size_t)pi[p] * KK;
        unsigned long long b0 = 0, b1 = 0;
#pragma unroll
        for (int k = 0; k < KK; ++k) {
            int c = row[k];
            if (c < 64) b0 |= 1ull << c; else b1 |= 1ull << (c - 64);
        }
        bits[t][0] = b0;
        bits[t][1] = b1;
        cls[t] = hqp[p];
    }
    if (t < PP) { smu[t] = mu[t]; ssd[t] = sd[t]; }
    __syncthreads();
    for (int idx = t; idx < 128 * PP; idx += 256) {
        const int c = idx >> 7;
        const int pl = idx & 127;
        const bool m = (c < 64) ? ((bits[pl][0] >> c) & 1) : ((bits[pl][1] >> (c - 64)) & 1);
        float v = 0.f;
        if (m) {
            float d = rwn[cls[pl] * PP + c] - smu[c];
            float s = ssd[c];
            v = expf(d * d / (2.0f * s * s));
        }
        CtabT[(size_t)c * NN + p0 + pl] = v;
    }
}

// ---------------- symmetric fused GEMM over upper-triangular blocks ----------------
// denom = sum_{p<q} exp(5*dot_pq) * (CtabT[cls q][p] + CtabT[cls p][q])
// Tiles 128(i) x 64(j); kept blocks: bj >= 2*bi  (count 4160). Per-element row<col mask
// handles the two diagonal-straddling block columns.
__global__ __launch_bounds__(256) void sim_kernel(
    const char* __restrict__ Gpb, const int* __restrict__ hqp,
    const float* __restrict__ CtabT, double* __restrict__ dpart) {
    const int L = blockIdx.x;        // 0..4159
    // invert start(bi) = bi*(129-bi):
    int bi = (int)((129.0f - sqrtf(16641.0f - 4.0f * (float)L)) * 0.5f);
    while (bi > 0 && bi * (129 - bi) > L) --bi;
    while ((bi + 1) * (129 - (bi + 1)) <= L) ++bi;
    const int bj = 2 * bi + (L - bi * (129 - bi));

    const int t = threadIdx.x;
    const int lane = t & 63;
    const int wv = t >> 6;
    const int i0w = bi * 128 + wv * 32;   // this wave's 32-row group base
    const int j0 = bj * 64;

    f32x16 acc[2] = {};

    const char* pa  = Gpb + (size_t)(i0w >> 5) * 8192 + lane * 8;      // 16 kc * 512B
    const char* pb0 = Gpb + (size_t)(j0 >> 5) * 8192 + lane * 8;
    const char* pb1 = pb0 + 8192;

#pragma unroll
    for (int kc = 0; kc < 16; ++kc) {
        long a  = *(const long*)(pa  + kc * 512);
        long b0 = *(const long*)(pb0 + kc * 512);
        long b1 = *(const long*)(pb1 + kc * 512);
        acc[0] = __builtin_amdgcn_mfma_f32_32x32x16_fp8_fp8(a, b0, acc[0], 0, 0, 0);
        acc[1] = __builtin_amdgcn_mfma_f32_32x32x16_fp8_fp8(a, b1, acc[1], 0, 0, 0);
    }

    // C/D layout (32x32): col = lane&31, row = (reg&3) + 8*(reg>>2) + 4*(lane>>5)
    const int cl = lane & 31, h = lane >> 5;
    const int col0 = j0 + cl;
    const int col1 = j0 + 32 + cl;
    const float* ct0 = CtabT + (size_t)hqp[col0] * NN;   // coef by column class
    const float* ct1 = CtabT + (size_t)hqp[col1] * NN;
    float partial = 0.f;
#pragma unroll
    for (int g = 0; g < 4; ++g) {
        const int rbase = i0w + 8 * g + 4 * h;
        const float4 cf0 = *(const float4*)(ct0 + rbase);   // C[row][cls col0]
        const float4 cf1 = *(const float4*)(ct1 + rbase);   // C[row][cls col1]
        const float* f0 = (const float*)&cf0;
        const float* f1 = (const float*)&cf1;
#pragma unroll
        for (int r = 0; r < 4; ++r) {
            const int row = rbase + r;
            const float* ctr = CtabT + (size_t)hqp[row] * NN;  // half-wave uniform
            const float c20 = ctr[col0];                        // coalesced over cl
            const float c21 = ctr[col1];
            const float e0 = __expf(acc[0][4 * g + r] * 5.0f);
            const float e1 = __expf(acc[1][4 * g + r] * 5.0f);
            partial += (row < col0) ? e0 * (f0[r] + c20) : 0.f;
            partial += (row < col1) ? e1 * (f1[r] + c21) : 0.f;
        }
    }
#pragma unroll
    for (int off = 32; off > 0; off >>= 1) partial += __shfl_down(partial, off);
    __shared__ float wsum[4];
    if (lane == 0) wsum[wv] = partial;
    __syncthreads();
    if (t == 0)
        atomicAdd(&dpart[L & 63], (double)(wsum[0] + wsum[1] + wsum[2] + wsum[3]));
}

// ---------------- finalize ----------------
__global__ void finalize_kernel(const double* __restrict__ dpart,
                                const double* __restrict__ ppart, float* __restrict__ out) {
    const int lane = threadIdx.x;  // 64
    double d = dpart[lane], p = ppart[lane];
#pragma unroll
    for (int off = 32; off > 0; off >>= 1) {
        d += __shfl_down(d, off);
        p += __shfl_down(p, off);
    }
    if (lane == 0) out[0] = (float)(log(d) - p * (5.0 / 4096.0));
}

extern "C" void kernel_launch(void* const* d_in, const int* in_sizes, int n_in,
                              void* d_out, int out_size, void* d_ws, size_t ws_size,
                              hipStream_t stream) {
    const float* x  = (const float*)d_in[0];
    const float* xa = (const float*)d_in[1];
    const float* pw = (const float*)d_in[2];
    const int* hq   = (const int*)d_in[3];
    const int* nq   = (const int*)d_in[4];
    float* out      = (float*)d_out;

    char* ws = (char*)d_ws;
    double* dpart = (double*)(ws + OFF_DPART);
    double* ppart = (double*)(ws + OFF_PPART);
    int* cnt      = (int*)(ws + OFF_CNT);
    float* mu     = (float*)(ws + OFF_MU);
    float* sd     = (float*)(ws + OFF_SD);
    float* rwn    = (float*)(ws + OFF_RWN);
    int* pi       = (int*)(ws + OFF_PI);
    int* invp     = (int*)(ws + OFF_INVP);
    int* hqp      = (int*)(ws + OFF_HQP);
    float* CtabT  = (float*)(ws + OFF_CTABT);
    char* Gpb     = (char*)(ws + OFF_G);

    prep_kernel<<<1, 1024, 0, stream>>>(hq, cnt, pi, invp, hqp, dpart, ppart);
    normalize_kernel<<<BB / 4, 256, 0, stream>>>(x, xa, invp, Gpb, ppart);
    protopd_kernel<<<PP, 256, 0, stream>>>(pw, cnt, rwn, mu, sd);
    ctab_kernel<<<NN / 128, 256, 0, stream>>>(pi, hqp, nq, rwn, mu, sd, CtabT);
    sim_kernel<<<4160, 256, 0, stream>>>(Gpb, hqp, CtabT, dpart);
    finalize_kernel<<<1, 64, 0, stream>>>(dpart, ppart, out);
}